// Round 5
// baseline (1752.735 us; speedup 1.0000x reference)
//
#include <hip/hip_runtime.h>

#define N_NODES 100000
#define N_EDGES 1600000
#define N_SUP 2
#define IN_DIM 256
#define OUT_DIM 64
#define N_TOT_EDGES (N_SUP * N_EDGES)   // 3,200,000
#define GM 64                           // GEMM M-tile per block
#define NBLK ((N_NODES + GM - 1) / GM)  // 1563

#define SHIFT_F 7                       // 128 nodes per fine bucket
#define NPB 128                         // nodes per bucket
#define NBUCK_F ((N_NODES + NPB - 1) / NPB)   // 782
#define CAP 5120                        // bucket capacity (mean 4096, +16 sigma)
#define BIN_CHUNK 32768                 // edges per bin block
#define BIN_BLOCKS ((N_TOT_EDGES + BIN_CHUNK - 1) / BIN_CHUNK)  // 98

typedef __attribute__((ext_vector_type(8))) short short8;   // 8 bf16
typedef __attribute__((ext_vector_type(4))) float floatx4;  // MFMA acc

__device__ inline ushort f2bf(float f) {          // fp32 -> bf16 RNE
    unsigned u = __float_as_uint(f);
    return (ushort)((u + 0x7fffu + ((u >> 16) & 1u)) >> 16);
}
__device__ inline float bf2f(ushort h) {
    return __uint_as_float(((unsigned)h) << 16);
}

// ---------------------------------------------------------------------------
// W pre-swizzle into mfma_f32_16x16x32_bf16 B-fragment order (unchanged R3).
// ---------------------------------------------------------------------------
__global__ __launch_bounds__(256) void wb_kernel(
    const float* __restrict__ W, ushort* __restrict__ Wb)
{
    int idx = blockIdx.x * 256 + threadIdx.x;      // 0..32767
    int j    = idx & 7;
    int lane = (idx >> 3) & 63;
    int nt   = (idx >> 9) & 7;
    int ks   = idx >> 12;
    int k = ks * 32 + (lane >> 4) * 8 + j;
    int n = nt * 16 + (lane & 15);
    Wb[idx] = f2bf(W[((size_t)(n >> 6) * IN_DIM + k) * OUT_DIM + (n & 63)]);
}

// ---------------------------------------------------------------------------
// MFMA GEMM (unchanged R3): psb[sup][node][64] bf16 = x @ W[sup], C[100000x128]
// ---------------------------------------------------------------------------
__global__ __launch_bounds__(256) void gemm_kernel(
    const float* __restrict__ x, const ushort* __restrict__ Wb,
    ushort* __restrict__ psb)
{
    __shared__ __align__(16) ushort xs[GM][264];
    const int row0 = blockIdx.x * GM;
    const int trow = threadIdx.x >> 6;
    const int tcol = threadIdx.x & 63;

#pragma unroll
    for (int j = 0; j < 16; ++j) {
        int r = j * 4 + trow;
        int gr = row0 + r;
        if (gr > N_NODES - 1) gr = N_NODES - 1;
        float4 v = ((const float4*)x)[(size_t)gr * 64 + tcol];
        ushort4 h;
        h.x = f2bf(v.x); h.y = f2bf(v.y); h.z = f2bf(v.z); h.w = f2bf(v.w);
        *(ushort4*)&xs[r][tcol * 4] = h;
    }
    __syncthreads();

    const int wave = threadIdx.x >> 6;
    const int lane = threadIdx.x & 63;
    const int q = lane >> 4;
    const int m = lane & 15;
    const int nt0 = wave * 2;

    floatx4 acc[4][2];
#pragma unroll
    for (int mt = 0; mt < 4; ++mt)
#pragma unroll
        for (int nt = 0; nt < 2; ++nt)
            acc[mt][nt] = (floatx4){0.f, 0.f, 0.f, 0.f};

    const short8* Wbv = (const short8*)Wb;
#pragma unroll
    for (int ks = 0; ks < 8; ++ks) {
        short8 b0 = Wbv[((ks * 8) + nt0) * 64 + lane];
        short8 b1 = Wbv[((ks * 8) + nt0 + 1) * 64 + lane];
#pragma unroll
        for (int mt = 0; mt < 4; ++mt) {
            short8 a = *(const short8*)&xs[mt * 16 + m][ks * 32 + q * 8];
            acc[mt][0] = __builtin_amdgcn_mfma_f32_16x16x32_bf16(a, b0, acc[mt][0], 0, 0, 0);
            acc[mt][1] = __builtin_amdgcn_mfma_f32_16x16x32_bf16(a, b1, acc[mt][1], 0, 0, 0);
        }
    }

#pragma unroll
    for (int mt = 0; mt < 4; ++mt) {
#pragma unroll
        for (int nt = 0; nt < 2; ++nt) {
            int col = wave * 32 + nt * 16 + m;
            int sup = col >> 6, ch = col & 63;
#pragma unroll
            for (int r = 0; r < 4; ++r) {
                int row = row0 + mt * 16 + q * 4 + r;
                if (row < N_NODES)
                    psb[((size_t)sup * N_NODES + row) * OUT_DIM + ch] =
                        f2bf(acc[mt][nt][r]);
            }
        }
    }
}

// ---------------------------------------------------------------------------
// bcur init: bucket cursor = fixed-stride region start (no CSR scan needed).
// ---------------------------------------------------------------------------
__global__ __launch_bounds__(256) void bcur_init_kernel(int* __restrict__ bcur)
{
    int b = blockIdx.x * 256 + threadIdx.x;
    if (b < NBUCK_F) bcur[b] = b * CAP;
}

// ---------------------------------------------------------------------------
// Bin: 98 blocks x 32768 edges, two passes over the chunk.
// Pass A: LDS histogram of dst>>7 (782 buckets). Reserve: ONE global atomic
// per bucket per block (77K total). Pass B: re-read (L2-hot), scatter packed
// records (val:32 | srcsup:18 | dst_lo:7) into block-private contiguous runs
// (~42 recs = 336 B) of the fixed-stride staging buffer -> L2-merged lines.
// ---------------------------------------------------------------------------
__global__ __launch_bounds__(256) void bin_kernel(
    const int* __restrict__ edge_src, const int* __restrict__ edge_dst,
    const float* __restrict__ edge_val,
    int* __restrict__ bcur, int2* __restrict__ sbuf)
{
    __shared__ int hist[NBUCK_F], rbase[NBUCK_F], rcnt[NBUCK_F];
    const int e0 = blockIdx.x * BIN_CHUNK;

    for (int t = threadIdx.x; t < NBUCK_F; t += 256) hist[t] = 0;
    __syncthreads();

    // pass A: bucket histogram
    for (int j = 0; j < BIN_CHUNK / 256; ++j) {
        int gid = e0 + j * 256 + threadIdx.x;
        if (gid < N_TOT_EDGES)
            atomicAdd(&hist[edge_dst[gid] >> SHIFT_F], 1);
    }
    __syncthreads();

    // reserve runs
    for (int t = threadIdx.x; t < NBUCK_F; t += 256) {
        rbase[t] = atomicAdd(&bcur[t], hist[t]);
        rcnt[t] = 0;
    }
    __syncthreads();

    // pass B: scatter into reserved runs
    for (int j = 0; j < BIN_CHUNK / 256; ++j) {
        int gid = e0 + j * 256 + threadIdx.x;
        if (gid < N_TOT_EDGES) {
            int dst = edge_dst[gid];
            int src = edge_src[gid];
            float val = edge_val[gid];
            int b = dst >> SHIFT_F;
            int srcsup = (gid >= N_EDGES ? N_NODES : 0) + src;
            int loc = atomicAdd(&rcnt[b], 1);
            sbuf[(size_t)rbase[b] + loc] =
                make_int2((srcsup << SHIFT_F) | (dst & (NPB - 1)),
                          __float_as_int(val));
        }
    }
}

// ---------------------------------------------------------------------------
// Merged scatter-gather: one block per 128-node bucket. fp32 accumulators in
// LDS (32 KB): acc[dst_lo][lane] -> lane=channel, bank-conflict-free (2-way).
// Wave-broadcast records (proven R3 pattern), 4-way psb-load ILP, native
// ds_add_f32 LDS atomics, then coalesced float4 write-out with fused ReLU.
// No global atomics, no CSR.
// ---------------------------------------------------------------------------
__global__ __launch_bounds__(256) void sg_kernel(
    const ushort* __restrict__ psb, const int* __restrict__ bcur,
    const int2* __restrict__ sbuf, float* __restrict__ out)
{
    __shared__ float acc[NPB][OUT_DIM];
    const int b = blockIdx.x;
    const int cnt = bcur[b] - b * CAP;
    const int2* sb = sbuf + (size_t)b * CAP;

    float4* av = (float4*)&acc[0][0];
    for (int i = threadIdx.x; i < NPB * OUT_DIM / 4; i += 256)
        av[i] = make_float4(0.f, 0.f, 0.f, 0.f);
    __syncthreads();

    const int wave = threadIdx.x >> 6;
    const int lane = threadIdx.x & 63;

    for (int t = wave * 64; t < cnt; t += 256) {
        const int c = min(64, cnt - t);
        int2 r = make_int2(0, 0);
        if (t + lane < cnt) r = sb[t + lane];
        int j = 0;
        for (; j + 4 <= c; j += 4) {
            int a0 = __shfl(r.x, j),     a1 = __shfl(r.x, j + 1);
            int a2 = __shfl(r.x, j + 2), a3 = __shfl(r.x, j + 3);
            float v0 = __int_as_float(__shfl(r.y, j));
            float v1 = __int_as_float(__shfl(r.y, j + 1));
            float v2 = __int_as_float(__shfl(r.y, j + 2));
            float v3 = __int_as_float(__shfl(r.y, j + 3));
            float p0 = bf2f(psb[(size_t)(a0 >> SHIFT_F) * OUT_DIM + lane]);
            float p1 = bf2f(psb[(size_t)(a1 >> SHIFT_F) * OUT_DIM + lane]);
            float p2 = bf2f(psb[(size_t)(a2 >> SHIFT_F) * OUT_DIM + lane]);
            float p3 = bf2f(psb[(size_t)(a3 >> SHIFT_F) * OUT_DIM + lane]);
            atomicAdd(&acc[a0 & (NPB - 1)][lane], p0 * v0);
            atomicAdd(&acc[a1 & (NPB - 1)][lane], p1 * v1);
            atomicAdd(&acc[a2 & (NPB - 1)][lane], p2 * v2);
            atomicAdd(&acc[a3 & (NPB - 1)][lane], p3 * v3);
        }
        for (; j < c; ++j) {
            int   a = __shfl(r.x, j);
            float v = __int_as_float(__shfl(r.y, j));
            float pp = bf2f(psb[(size_t)(a >> SHIFT_F) * OUT_DIM + lane]);
            atomicAdd(&acc[a & (NPB - 1)][lane], pp * v);
        }
    }
    __syncthreads();

    // write-out with fused ReLU: 2048 float4, 8 per thread, coalesced
    const int n0 = b << SHIFT_F;
    for (int i = threadIdx.x; i < NPB * OUT_DIM / 4; i += 256) {
        int node = n0 + (i >> 4);          // 16 float4 per node row
        if (node < N_NODES) {
            float4 v = av[i];
            v.x = fmaxf(v.x, 0.f);
            v.y = fmaxf(v.y, 0.f);
            v.z = fmaxf(v.z, 0.f);
            v.w = fmaxf(v.w, 0.f);
            ((float4*)out)[(size_t)node * 16 + (i & 15)] = v;
        }
    }
}

extern "C" void kernel_launch(void* const* d_in, const int* in_sizes, int n_in,
                              void* d_out, int out_size, void* d_ws, size_t ws_size,
                              hipStream_t stream)
{
    const float* x        = (const float*)d_in[0];
    const float* W        = (const float*)d_in[1];
    const float* edge_val = (const float*)d_in[2];
    const int*   edge_src = (const int*)d_in[3];
    const int*   edge_dst = (const int*)d_in[4];
    float* out = (float*)d_out;

    // workspace layout (total 57,699,392 B, well under the proven 78 MB):
    //   psb  [2*100000*64 bf16]   @ 0           (25,600,000)
    //   sbuf [782*5120 int2]      @ 25,600,000  (32,030,720)
    //   bcur [782 int]            @ 57,630,720  (3,128; pad to 3,136)
    //   Wb   [32768 ushort]       @ 57,633,856  (65,536)
    ushort* psb  = (ushort*)d_ws;
    char* p = (char*)d_ws;
    int2* sbuf   = (int2*)(p + 25600000);
    int*  bcur   = (int*)(p + 57630720);
    ushort* Wb   = (ushort*)(p + 57633856);

    wb_kernel<<<128, 256, 0, stream>>>(W, Wb);
    gemm_kernel<<<NBLK, 256, 0, stream>>>(x, Wb, psb);

    bcur_init_kernel<<<(NBUCK_F + 255) / 256, 256, 0, stream>>>(bcur);
    bin_kernel<<<BIN_BLOCKS, 256, 0, stream>>>(edge_src, edge_dst, edge_val,
                                               bcur, sbuf);
    sg_kernel<<<NBUCK_F, 256, 0, stream>>>(psb, bcur, sbuf, out);
}

// Round 6
// 393.628 us; speedup vs baseline: 4.4528x; 4.4528x over previous
//
#include <hip/hip_runtime.h>

#define N_NODES 100000
#define N_EDGES 1600000
#define N_SUP 2
#define IN_DIM 256
#define OUT_DIM 64
#define N_TOT_EDGES (N_SUP * N_EDGES)   // 3,200,000
#define GM 64                           // GEMM M-tile per block
#define NBLK ((N_NODES + GM - 1) / GM)  // 1563

#define SHIFT 10                        // 1024 nodes per bucket
#define NBUCK 98                        // ceil(100000/1024)
#define CHUNK 4096                      // edges per bin/bhist block
#define BGRID ((N_TOT_EDGES + CHUNK - 1) / CHUNK)  // 782

typedef __attribute__((ext_vector_type(8))) short short8;   // 8 bf16
typedef __attribute__((ext_vector_type(4))) float floatx4;  // MFMA acc
typedef unsigned long long u64;

__device__ inline ushort f2bf(float f) {          // fp32 -> bf16 RNE
    unsigned u = __float_as_uint(f);
    return (ushort)((u + 0x7fffu + ((u >> 16) & 1u)) >> 16);
}
__device__ inline float bf2f(ushort h) {
    return __uint_as_float(((unsigned)h) << 16);
}

// ---------------------------------------------------------------------------
// W pre-swizzle into mfma_f32_16x16x32_bf16 B-fragment order (unchanged R3).
// ---------------------------------------------------------------------------
__global__ __launch_bounds__(256) void wb_kernel(
    const float* __restrict__ W, ushort* __restrict__ Wb)
{
    int idx = blockIdx.x * 256 + threadIdx.x;      // 0..32767
    int j    = idx & 7;
    int lane = (idx >> 3) & 63;
    int nt   = (idx >> 9) & 7;
    int ks   = idx >> 12;
    int k = ks * 32 + (lane >> 4) * 8 + j;
    int n = nt * 16 + (lane & 15);
    Wb[idx] = f2bf(W[((size_t)(n >> 6) * IN_DIM + k) * OUT_DIM + (n & 63)]);
}

// ---------------------------------------------------------------------------
// MFMA GEMM (unchanged R3): psb[sup][node][64] bf16 = x @ W[sup], C[100000x128]
// ---------------------------------------------------------------------------
__global__ __launch_bounds__(256) void gemm_kernel(
    const float* __restrict__ x, const ushort* __restrict__ Wb,
    ushort* __restrict__ psb)
{
    __shared__ __align__(16) ushort xs[GM][264];
    const int row0 = blockIdx.x * GM;
    const int trow = threadIdx.x >> 6;
    const int tcol = threadIdx.x & 63;

#pragma unroll
    for (int j = 0; j < 16; ++j) {
        int r = j * 4 + trow;
        int gr = row0 + r;
        if (gr > N_NODES - 1) gr = N_NODES - 1;
        float4 v = ((const float4*)x)[(size_t)gr * 64 + tcol];
        ushort4 h;
        h.x = f2bf(v.x); h.y = f2bf(v.y); h.z = f2bf(v.z); h.w = f2bf(v.w);
        *(ushort4*)&xs[r][tcol * 4] = h;
    }
    __syncthreads();

    const int wave = threadIdx.x >> 6;
    const int lane = threadIdx.x & 63;
    const int q = lane >> 4;
    const int m = lane & 15;
    const int nt0 = wave * 2;

    floatx4 acc[4][2];
#pragma unroll
    for (int mt = 0; mt < 4; ++mt)
#pragma unroll
        for (int nt = 0; nt < 2; ++nt)
            acc[mt][nt] = (floatx4){0.f, 0.f, 0.f, 0.f};

    const short8* Wbv = (const short8*)Wb;
#pragma unroll
    for (int ks = 0; ks < 8; ++ks) {
        short8 b0 = Wbv[((ks * 8) + nt0) * 64 + lane];
        short8 b1 = Wbv[((ks * 8) + nt0 + 1) * 64 + lane];
#pragma unroll
        for (int mt = 0; mt < 4; ++mt) {
            short8 a = *(const short8*)&xs[mt * 16 + m][ks * 32 + q * 8];
            acc[mt][0] = __builtin_amdgcn_mfma_f32_16x16x32_bf16(a, b0, acc[mt][0], 0, 0, 0);
            acc[mt][1] = __builtin_amdgcn_mfma_f32_16x16x32_bf16(a, b1, acc[mt][1], 0, 0, 0);
        }
    }

#pragma unroll
    for (int mt = 0; mt < 4; ++mt) {
#pragma unroll
        for (int nt = 0; nt < 2; ++nt) {
            int col = wave * 32 + nt * 16 + m;
            int sup = col >> 6, ch = col & 63;
#pragma unroll
            for (int r = 0; r < 4; ++r) {
                int row = row0 + mt * 16 + q * 4 + r;
                if (row < N_NODES)
                    psb[((size_t)sup * N_NODES + row) * OUT_DIM + ch] =
                        f2bf(acc[mt][nt][r]);
            }
        }
    }
}

// ---------------------------------------------------------------------------
// Zero the 98 global bucket counters.
// ---------------------------------------------------------------------------
__global__ void zinit_kernel(int* __restrict__ bhist)
{
    if (threadIdx.x < NBUCK) bhist[threadIdx.x] = 0;
}

// ---------------------------------------------------------------------------
// Coarse bucket histogram: LDS 98 counters per block, one global atomic per
// (block, bucket) = 76K atomics total (vs 3.2M per-node in the old hist).
// ---------------------------------------------------------------------------
__global__ __launch_bounds__(256) void bhist_kernel(
    const int* __restrict__ edge_dst, int* __restrict__ bhist)
{
    __shared__ int h[NBUCK];
    if (threadIdx.x < NBUCK) h[threadIdx.x] = 0;
    __syncthreads();
    const int base = blockIdx.x * CHUNK + threadIdx.x;
    for (int j = 0; j < CHUNK / 256; ++j) {
        int gid = base + j * 256;
        if (gid < N_TOT_EDGES)
            atomicAdd(&h[edge_dst[gid] >> SHIFT], 1);
    }
    __syncthreads();
    if (threadIdx.x < NBUCK) {
        int v = h[threadIdx.x];
        if (v) atomicAdd(&bhist[threadIdx.x], v);
    }
}

// ---------------------------------------------------------------------------
// Exclusive scan of 98 bucket counts -> exact staging bases; init bin cursors.
// ---------------------------------------------------------------------------
__global__ void bscan_kernel(const int* __restrict__ bhist,
                             int* __restrict__ bbase, int* __restrict__ bcur)
{
    if (threadIdx.x == 0 && blockIdx.x == 0) {
        int acc = 0;
        for (int i = 0; i < NBUCK; ++i) {
            bbase[i] = acc;
            bcur[i] = acc;
            acc += bhist[i];
        }
    }
}

// ---------------------------------------------------------------------------
// Bin (unchanged R4 structure): records held in registers, LDS block-hist,
// one reservation atomic per touched bucket, contiguous run writes into
// EXACT-size staging regions. rec = (val:32 | srcsup:18 | dst_lo:10).
// ---------------------------------------------------------------------------
__global__ __launch_bounds__(256) void bin_kernel(
    const int* __restrict__ edge_src, const int* __restrict__ edge_dst,
    const float* __restrict__ edge_val,
    int* __restrict__ bcur, u64* __restrict__ sbuf)
{
    __shared__ int hist[NBUCK], gbase[NBUCK], cnt[NBUCK];
    const int base = blockIdx.x * CHUNK + threadIdx.x;

    u64 pk[16];
    int bk[16];
    if (threadIdx.x < NBUCK) hist[threadIdx.x] = 0;
    __syncthreads();

#pragma unroll
    for (int j = 0; j < 16; ++j) {
        int gid = base + j * 256;
        bk[j] = -1;
        if (gid < N_TOT_EDGES) {
            int dst = edge_dst[gid];
            int src = edge_src[gid];
            float val = edge_val[gid];
            int srcsup = (gid >= N_EDGES ? N_NODES : 0) + src;
            bk[j] = dst >> SHIFT;
            pk[j] = ((u64)__float_as_uint(val) << 32)
                  | (u64)(((unsigned)srcsup << SHIFT) | (unsigned)(dst & 1023));
            atomicAdd(&hist[bk[j]], 1);
        }
    }
    __syncthreads();
    if (threadIdx.x < NBUCK) {
        int h = hist[threadIdx.x];
        gbase[threadIdx.x] = (h > 0) ? atomicAdd(&bcur[threadIdx.x], h) : 0;
        cnt[threadIdx.x] = 0;
    }
    __syncthreads();
#pragma unroll
    for (int j = 0; j < 16; ++j) {
        if (bk[j] >= 0) {
            int loc = atomicAdd(&cnt[bk[j]], 1);
            sbuf[(size_t)gbase[bk[j]] + loc] = pk[j];
        }
    }
}

// ---------------------------------------------------------------------------
// Group + per-node CSR build, one 1024-thr block per bucket:
//   pass 1: LDS hist of 1024 local node counts (streaming coalesced reads)
//   LDS Hillis-Steele scan -> per-node CSR offsets; write start[] (global)
//   pass 2: LDS cursors, scatter records into final erec (262 KB region,
//           single-XCD -> L2-merged lines).
// Staging offsets == CSR offsets (both exact), so sb = sbuf + bbase[b].
// ---------------------------------------------------------------------------
__global__ __launch_bounds__(1024) void group_kernel(
    const u64* __restrict__ sbuf, const int* __restrict__ bhist,
    const int* __restrict__ bbase, int* __restrict__ start,
    int2* __restrict__ erec)
{
    __shared__ int h[1024];
    __shared__ int sc[1024];
    const int b = blockIdx.x;
    const int cnt = bhist[b];
    const int base = bbase[b];
    const u64* sb = sbuf + base;

    h[threadIdx.x] = 0;
    __syncthreads();
    for (int i = threadIdx.x; i < cnt; i += 1024)
        atomicAdd(&h[(int)(sb[i] & 1023u)], 1);
    __syncthreads();

    int v = h[threadIdx.x];
    sc[threadIdx.x] = v;
    __syncthreads();
    for (int off = 1; off < 1024; off <<= 1) {
        int add = (threadIdx.x >= off) ? sc[threadIdx.x - off] : 0;
        __syncthreads();
        sc[threadIdx.x] += add;
        __syncthreads();
    }
    const int excl = sc[threadIdx.x] - v;

    const int n = (b << SHIFT) + threadIdx.x;
    if (n <= N_NODES) start[n] = base + excl;

    __syncthreads();
    h[threadIdx.x] = base + excl;      // reuse as per-node cursor
    __syncthreads();

    for (int i = threadIdx.x; i < cnt; i += 1024) {
        u64 p = sb[i];
        int dl = (int)(p & 1023u);
        int pos = atomicAdd(&h[dl], 1);
        erec[pos] = make_int2((int)((p >> SHIFT) & 0x3FFFFu), (int)(p >> 32));
    }
}

// ---------------------------------------------------------------------------
// Gather (unchanged R4): one wave per node, lane = channel, bf16 psb rows,
// 4-way load ILP, fused ReLU, 25000 blocks of latency-hiding parallelism.
// ---------------------------------------------------------------------------
__global__ __launch_bounds__(256) void gather_kernel(
    const ushort* __restrict__ psb, const int* __restrict__ start,
    const int2* __restrict__ erec, float* __restrict__ out)
{
    const int n = blockIdx.x * 4 + (threadIdx.x >> 6);
    const int lane = threadIdx.x & 63;
    const int s = start[n];
    const int e = start[n + 1];

    float acc = 0.f;
    for (int base = s; base < e; base += 64) {
        const int cnt = min(64, e - base);
        int2 r = make_int2(0, 0);
        if (base + lane < e) r = erec[base + lane];
        int j = 0;
        for (; j + 4 <= cnt; j += 4) {
            int   r0 = __shfl(r.x, j),     r1 = __shfl(r.x, j + 1);
            int   r2 = __shfl(r.x, j + 2), r3 = __shfl(r.x, j + 3);
            float v0 = __int_as_float(__shfl(r.y, j));
            float v1 = __int_as_float(__shfl(r.y, j + 1));
            float v2 = __int_as_float(__shfl(r.y, j + 2));
            float v3 = __int_as_float(__shfl(r.y, j + 3));
            float p0 = bf2f(psb[(size_t)r0 * OUT_DIM + lane]);
            float p1 = bf2f(psb[(size_t)r1 * OUT_DIM + lane]);
            float p2 = bf2f(psb[(size_t)r2 * OUT_DIM + lane]);
            float p3 = bf2f(psb[(size_t)r3 * OUT_DIM + lane]);
            acc = fmaf(p0, v0, acc);
            acc = fmaf(p1, v1, acc);
            acc = fmaf(p2, v2, acc);
            acc = fmaf(p3, v3, acc);
        }
        for (; j < cnt; ++j) {
            int   row = __shfl(r.x, j);
            float val = __int_as_float(__shfl(r.y, j));
            acc = fmaf(bf2f(psb[(size_t)row * OUT_DIM + lane]), val, acc);
        }
    }
    out[(size_t)n * OUT_DIM + lane] = fmaxf(acc, 0.f);
}

extern "C" void kernel_launch(void* const* d_in, const int* in_sizes, int n_in,
                              void* d_out, int out_size, void* d_ws, size_t ws_size,
                              hipStream_t stream)
{
    const float* x        = (const float*)d_in[0];
    const float* W        = (const float*)d_in[1];
    const float* edge_val = (const float*)d_in[2];
    const int*   edge_src = (const int*)d_in[3];
    const int*   edge_dst = (const int*)d_in[4];
    float* out = (float*)d_out;

    // workspace layout (total 77,266,768 B <= R2's proven 77.67 MB):
    //   psb   [2*100000*64 bf16] @ 0           (25,600,000)
    //   sbuf  [3.2M u64]         @ 25,600,000  (25,600,000)  exact-size staging
    //   erec  [3.2M int2]        @ 51,200,000  (25,600,000)
    //   start [N+1 int]          @ 76,800,000  (400,016)
    //   bhist [98 int]           @ 77,200,016  (416)
    //   bbase [98 int]           @ 77,200,432  (400)
    //   bcur  [98 int]           @ 77,200,832  (400)
    //   Wb    [32768 ushort]     @ 77,201,232  (65,536)  16B-aligned
    ushort* psb  = (ushort*)d_ws;
    char* p = (char*)d_ws;
    u64*  sbuf  = (u64*)(p + 25600000);
    int2* erec  = (int2*)(p + 51200000);
    int*  start = (int*)(p + 76800000);
    int*  bhist = (int*)(p + 77200016);
    int*  bbase = (int*)(p + 77200432);
    int*  bcur  = (int*)(p + 77200832);
    ushort* Wb  = (ushort*)(p + 77201232);

    wb_kernel<<<128, 256, 0, stream>>>(W, Wb);
    gemm_kernel<<<NBLK, 256, 0, stream>>>(x, Wb, psb);

    zinit_kernel<<<1, 128, 0, stream>>>(bhist);
    bhist_kernel<<<BGRID, 256, 0, stream>>>(edge_dst, bhist);
    bscan_kernel<<<1, 64, 0, stream>>>(bhist, bbase, bcur);
    bin_kernel<<<BGRID, 256, 0, stream>>>(edge_src, edge_dst, edge_val,
                                          bcur, sbuf);
    group_kernel<<<NBUCK, 1024, 0, stream>>>(sbuf, bhist, bbase, start, erec);

    gather_kernel<<<N_NODES / 4, 256, 0, stream>>>(psb, start, erec, out);
}